// Round 1
// 1021.371 us; speedup vs baseline: 1.0657x; 1.0657x over previous
//
#include <hip/hip_runtime.h>
#include <cstdint>
#include <cstddef>

#define N_NODES 50000
#define N_EDGES 400000
#define D_IN 512
#define D_OUT 512
#define D_K 1024            // packed K: [Xagg | Xb]
#define M_PAD 50048         // 391 * 128
#define MBLKS 391           // M_PAD / 128
#define NEG_SLOPE 0.01f
#define FILL 2.0f
#define SCAN_NBLK 196       // ceil(50000/256)

#define GEMM_NWG (3 * MBLKS * 4)   // 4692 blocks (1-D grid, swizzled)
#define GEMM_Q (GEMM_NWG / 8)      // 586
#define GEMM_R (GEMM_NWG % 8)      // 4

typedef __bf16 bf16x8 __attribute__((ext_vector_type(8)));
typedef float f32x4 __attribute__((ext_vector_type(4)));
typedef unsigned short ushort8v __attribute__((ext_vector_type(8)));

__device__ inline unsigned short f2bf(float f) {
    unsigned int u = __float_as_uint(f);
    unsigned int r = (u + 0x7FFFu + ((u >> 16) & 1u)) >> 16;
    return (unsigned short)r;
}
__device__ inline float bf2f(unsigned short b) {
    return __uint_as_float(((unsigned int)b) << 16);
}

// ---------------- norm / CSR construction ----------------

__global__ void init_kernel(float* deg, int* counts, int* cursor) {
    int i = blockIdx.x * blockDim.x + threadIdx.x;
    if (i < N_NODES) { deg[i] = FILL; counts[i] = 0; cursor[i] = 0; }
}

__global__ void edge_deg_kernel(const int* __restrict__ adj, const float* __restrict__ w,
                                float* deg, int* counts) {
    int e = blockIdx.x * blockDim.x + threadIdx.x;
    if (e < N_EDGES) {
        int d = adj[N_EDGES + e];
        atomicAdd(&deg[d], w[e]);
        atomicAdd(&counts[d], 1);
    }
}

__global__ void dis_kernel(const float* __restrict__ deg, float* __restrict__ dis) {
    int i = blockIdx.x * blockDim.x + threadIdx.x;
    if (i < N_NODES) {
        float g = deg[i];
        dis[i] = (g > 0.0f) ? rsqrtf(g) : 0.0f;
    }
}

// hierarchical exclusive scan of counts[N] -> offsets[N+1]
__global__ __launch_bounds__(256)
void scan1_kernel(const int* __restrict__ counts, int* __restrict__ offsets,
                  int* __restrict__ bsum) {
    __shared__ int wsum[4];
    int tid = threadIdx.x;
    int lane = tid & 63, wid = tid >> 6;
    int i = blockIdx.x * 256 + tid;
    int orig = (i < N_NODES) ? counts[i] : 0;
    int v = orig;
    #pragma unroll
    for (int d = 1; d < 64; d <<= 1) {
        int t = __shfl_up(v, d, 64);
        if (lane >= d) v += t;
    }
    if (lane == 63) wsum[wid] = v;
    __syncthreads();
    int add = 0;
    for (int ww = 0; ww < wid; ++ww) add += wsum[ww];
    int incl = v + add;
    if (i < N_NODES) offsets[i] = incl - orig;
    if (tid == 255) bsum[blockIdx.x] = incl;
}

__global__ __launch_bounds__(256)
void scan2_kernel(const int* __restrict__ bsum, int* __restrict__ bscan) {
    __shared__ int wsum[4];
    int tid = threadIdx.x;
    int lane = tid & 63, wid = tid >> 6;
    int orig = (tid < SCAN_NBLK) ? bsum[tid] : 0;
    int v = orig;
    #pragma unroll
    for (int d = 1; d < 64; d <<= 1) {
        int t = __shfl_up(v, d, 64);
        if (lane >= d) v += t;
    }
    if (lane == 63) wsum[wid] = v;
    __syncthreads();
    int add = 0;
    for (int ww = 0; ww < wid; ++ww) add += wsum[ww];
    int incl = v + add;
    if (tid < SCAN_NBLK) bscan[tid] = incl - orig;
    if (tid == 255) bscan[SCAN_NBLK] = incl;
}

__global__ __launch_bounds__(256)
void scan3_kernel(int* __restrict__ offsets, const int* __restrict__ bscan) {
    int i = blockIdx.x * 256 + threadIdx.x;
    if (i < N_NODES) offsets[i] += bscan[blockIdx.x];
    if (i == N_NODES) offsets[N_NODES] = bscan[SCAN_NBLK];
}

__global__ void fill_kernel(const int* __restrict__ adj, const float* __restrict__ w,
                            const float* __restrict__ dis, const int* __restrict__ offsets,
                            int* cursor, int* __restrict__ csr_src, float* __restrict__ csr_val) {
    int e = blockIdx.x * blockDim.x + threadIdx.x;
    if (e < N_EDGES) {
        int s = adj[e];
        int d = adj[N_EDGES + e];
        float v = dis[s] * w[e] * dis[d];
        int pos = offsets[d] + atomicAdd(&cursor[d], 1);
        csr_src[pos] = s;
        csr_val[pos] = v;
    }
}

// ---------------- conversions ----------------

__global__ void convert_w_kernel(const float* __restrict__ W, const float* __restrict__ Wres,
                                 unsigned short* __restrict__ Wcb) {
    int idx = blockIdx.x * blockDim.x + threadIdx.x;
    if (idx < D_OUT * D_K) {
        int n = idx >> 10, k = idx & 1023;
        float v = (k < D_IN) ? W[(size_t)k * D_OUT + n] : Wres[(size_t)(k - D_IN) * D_OUT + n];
        Wcb[idx] = f2bf(v);
    }
}

__global__ void convert_x_kernel(const float* __restrict__ x0, const float* __restrict__ x1,
                                 const float* __restrict__ x2, unsigned short* __restrict__ Xcat) {
    size_t gid = (size_t)blockIdx.x * blockDim.x + threadIdx.x;
    size_t base = gid * 8;
    if (base >= (size_t)3 * M_PAD * D_IN) return;
    int conv = (int)(base / ((size_t)M_PAD * D_IN));
    size_t rem = base - (size_t)conv * M_PAD * D_IN;
    int row = (int)(rem >> 9);
    int col = (int)(rem & 511);
    unsigned short* dst = Xcat + ((size_t)conv * M_PAD + row) * D_K;
    ushort8v o;
    if (row < N_NODES) {
        const float* xs = (conv == 0 ? x0 : (conv == 1 ? x1 : x2));
        const float4 v0 = *reinterpret_cast<const float4*>(xs + (size_t)row * D_IN + col);
        const float4 v1 = *reinterpret_cast<const float4*>(xs + (size_t)row * D_IN + col + 4);
        o[0] = f2bf(v0.x); o[1] = f2bf(v0.y); o[2] = f2bf(v0.z); o[3] = f2bf(v0.w);
        o[4] = f2bf(v1.x); o[5] = f2bf(v1.y); o[6] = f2bf(v1.z); o[7] = f2bf(v1.w);
    } else {
        #pragma unroll
        for (int j = 0; j < 8; ++j) o[j] = 0;
        *reinterpret_cast<ushort8v*>(dst + col) = o;     // zero Xagg half of pad row
    }
    *reinterpret_cast<ushort8v*>(dst + D_IN + col) = o;  // Xb half
}

// ---------------- gather: Xagg = A_norm @ Xb (incl. self loop) ----------------
// One wave per node; lane reads 8 bf16 (16 B). grid.y = conv index.

__global__ __launch_bounds__(256)
void gather_kernel(unsigned short* __restrict__ Xcat, const int* __restrict__ offsets,
                   const int* __restrict__ csr_src, const float* __restrict__ csr_val,
                   const float* __restrict__ dis) {
    int wid = threadIdx.x >> 6;
    int lane = threadIdx.x & 63;
    int node = blockIdx.x * 4 + wid;
    if (node >= N_NODES) return;
    unsigned short* xc = Xcat + (size_t)blockIdx.y * M_PAD * D_K;
    const unsigned short* xb = xc + D_IN + (size_t)lane * 8;
    float dn = dis[node];
    float selfw = FILL * dn * dn;
    ushort8v hs = *reinterpret_cast<const ushort8v*>(xb + (size_t)node * D_K);
    float a[8];
    #pragma unroll
    for (int j = 0; j < 8; ++j) a[j] = selfw * bf2f(hs[j]);
    int beg = offsets[node], end = offsets[node + 1];
    int e = beg;
    // 4-deep unroll: 4 independent 16B row loads in flight per wave
    for (; e + 3 < end; e += 4) {
        int s0 = csr_src[e], s1 = csr_src[e + 1], s2 = csr_src[e + 2], s3 = csr_src[e + 3];
        float v0 = csr_val[e], v1 = csr_val[e + 1], v2 = csr_val[e + 2], v3 = csr_val[e + 3];
        ushort8v h0 = *reinterpret_cast<const ushort8v*>(xb + (size_t)s0 * D_K);
        ushort8v h1 = *reinterpret_cast<const ushort8v*>(xb + (size_t)s1 * D_K);
        ushort8v h2 = *reinterpret_cast<const ushort8v*>(xb + (size_t)s2 * D_K);
        ushort8v h3 = *reinterpret_cast<const ushort8v*>(xb + (size_t)s3 * D_K);
        #pragma unroll
        for (int j = 0; j < 8; ++j) a[j] += v0 * bf2f(h0[j]);
        #pragma unroll
        for (int j = 0; j < 8; ++j) a[j] += v1 * bf2f(h1[j]);
        #pragma unroll
        for (int j = 0; j < 8; ++j) a[j] += v2 * bf2f(h2[j]);
        #pragma unroll
        for (int j = 0; j < 8; ++j) a[j] += v3 * bf2f(h3[j]);
    }
    for (; e < end; ++e) {
        int s0 = csr_src[e];
        float v0 = csr_val[e];
        ushort8v h0 = *reinterpret_cast<const ushort8v*>(xb + (size_t)s0 * D_K);
        #pragma unroll
        for (int j = 0; j < 8; ++j) a[j] += v0 * bf2f(h0[j]);
    }
    ushort8v o;
    #pragma unroll
    for (int j = 0; j < 8; ++j) o[j] = f2bf(a[j]);
    *reinterpret_cast<ushort8v*>(xc + (size_t)node * D_K + lane * 8) = o;
}

// ---------------- GEMM: out = leaky(Xcat[3*M_PAD][1024] @ Wcb^T) ----------------

__device__ inline void gload_lds16(const void* g, void* l) {
    __builtin_amdgcn_global_load_lds(
        (const __attribute__((address_space(1))) void*)g,
        (__attribute__((address_space(3))) void*)l, 16, 0, 0);
}

__global__ __launch_bounds__(256)
void gemm_kernel(const unsigned short* __restrict__ Xcat, const unsigned short* __restrict__ Wcb,
                 float* __restrict__ out) {
    __shared__ __align__(16) __bf16 Asm[2][128 * 32];
    __shared__ __align__(16) __bf16 Bsm[2][128 * 32];
    int tid = threadIdx.x;
    int lane = tid & 63, wid = tid >> 6;
    int wm = wid & 1, wn = wid >> 1;

    // bijective XCD-chunk swizzle (m204): each XCD gets a contiguous chunk of
    // work ids; col-block is innermost so the 4 col-blocks sharing an A-panel
    // run back-to-back on the same XCD's L2.
    int bid = blockIdx.x;
    int xcd = bid & 7, sidx = bid >> 3;
    int wg = (xcd < GEMM_R ? xcd * (GEMM_Q + 1)
                           : GEMM_R * (GEMM_Q + 1) + (xcd - GEMM_R) * GEMM_Q) + sidx;
    int mblk = wg >> 2;              // 0..1172  (A-panel id)
    int colBase = (wg & 3) * 128;    // 0,128,256,384
    int conv = mblk / MBLKS;
    int rowBase = mblk * 128;
    int nodeBase = rowBase - conv * M_PAD;

    f32x4 acc[4][4];
    #pragma unroll
    for (int i = 0; i < 4; ++i)
        #pragma unroll
        for (int j = 0; j < 4; ++j)
            acc[i][j] = (f32x4){0.f, 0.f, 0.f, 0.f};

    const unsigned short* Ag = Xcat + (size_t)rowBase * D_K;
    const unsigned short* Bg = Wcb + (size_t)colBase * D_K;

    // prologue: stage k-step 0 into buffer 0
    #pragma unroll
    for (int t = 0; t < 2; ++t) {
        int idx = t * 256 + tid;
        int row = idx >> 2, ch = idx & 3;
        gload_lds16(Ag + (size_t)row * D_K + ch * 8, (char*)Asm[0] + idx * 16);
        gload_lds16(Bg + (size_t)row * D_K + ch * 8, (char*)Bsm[0] + idx * 16);
    }
    __syncthreads();

    int cur = 0;
    #pragma unroll 1
    for (int k0 = 0; k0 < D_K; k0 += 32) {
        // issue next k-step's loads into the other buffer BEFORE compute
        if (k0 + 32 < D_K) {
            #pragma unroll
            for (int t = 0; t < 2; ++t) {
                int idx = t * 256 + tid;
                int row = idx >> 2, ch = idx & 3;
                gload_lds16(Ag + (size_t)row * D_K + (k0 + 32) + ch * 8,
                            (char*)Asm[cur ^ 1] + idx * 16);
                gload_lds16(Bg + (size_t)row * D_K + (k0 + 32) + ch * 8,
                            (char*)Bsm[cur ^ 1] + idx * 16);
            }
        }
        bf16x8 aF[4], bF[4];
        #pragma unroll
        for (int i = 0; i < 4; ++i)
            aF[i] = *reinterpret_cast<const bf16x8*>(
                &Asm[cur][(wm * 64 + i * 16 + (lane & 15)) * 32 + (lane >> 4) * 8]);
        #pragma unroll
        for (int j = 0; j < 4; ++j)
            bF[j] = *reinterpret_cast<const bf16x8*>(
                &Bsm[cur][(wn * 64 + j * 16 + (lane & 15)) * 32 + (lane >> 4) * 8]);
        #pragma unroll
        for (int i = 0; i < 4; ++i)
            #pragma unroll
            for (int j = 0; j < 4; ++j)
                acc[i][j] = __builtin_amdgcn_mfma_f32_16x16x32_bf16(aF[i], bF[j], acc[i][j], 0, 0, 0);
        // drain this iteration's prefetch + sync; next buffer is then ready
        __syncthreads();
        cur ^= 1;
    }

    int q = lane >> 4, c = lane & 15;
    float* obase = out + (size_t)conv * N_NODES * D_OUT;
    #pragma unroll
    for (int i = 0; i < 4; ++i)
        #pragma unroll
        for (int j = 0; j < 4; ++j)
            #pragma unroll
            for (int r = 0; r < 4; ++r) {
                int node = nodeBase + wm * 64 + i * 16 + q * 4 + r;
                int col = colBase + wn * 64 + j * 16 + c;
                if (node < N_NODES) {
                    float v = acc[i][j][r];
                    v = (v >= 0.0f) ? v : NEG_SLOPE * v;
                    __builtin_nontemporal_store(v, obase + (size_t)node * D_OUT + col);
                }
            }
}

// ---------------- launch ----------------

extern "C" void kernel_launch(void* const* d_in, const int* in_sizes, int n_in,
                              void* d_out, int out_size, void* d_ws, size_t ws_size,
                              hipStream_t stream) {
    const float* x0 = (const float*)d_in[0];
    const float* x1 = (const float*)d_in[1];
    const float* x2 = (const float*)d_in[2];
    const int* adj = (const int*)d_in[3];
    const float* aw = (const float*)d_in[4];
    const float* W = (const float*)d_in[5];
    const float* Wres = (const float*)d_in[6];
    float* out = (float*)d_out;

    char* base = (char*)d_ws;
    size_t off = 0;
    auto carve = [&](size_t bytes) -> void* {
        void* p = base + off;
        off += (bytes + 255) & ~(size_t)255;
        return p;
    };
    float* deg     = (float*)carve(sizeof(float) * N_NODES);
    float* dis     = (float*)carve(sizeof(float) * N_NODES);
    int*   counts  = (int*)carve(sizeof(int) * N_NODES);
    int*   offsets = (int*)carve(sizeof(int) * (N_NODES + 1));
    int*   cursor  = (int*)carve(sizeof(int) * N_NODES);
    int*   bsum    = (int*)carve(sizeof(int) * SCAN_NBLK);
    int*   bscan   = (int*)carve(sizeof(int) * (SCAN_NBLK + 1));
    int*   csr_src = (int*)carve(sizeof(int) * N_EDGES);
    float* csr_val = (float*)carve(sizeof(float) * N_EDGES);
    unsigned short* Wcb  = (unsigned short*)carve(sizeof(unsigned short) * D_OUT * D_K);
    unsigned short* Xcat = (unsigned short*)carve(sizeof(unsigned short) * (size_t)3 * M_PAD * D_K);

    // norm + CSR
    init_kernel<<<(N_NODES + 255) / 256, 256, 0, stream>>>(deg, counts, cursor);
    edge_deg_kernel<<<(N_EDGES + 255) / 256, 256, 0, stream>>>(adj, aw, deg, counts);
    dis_kernel<<<(N_NODES + 255) / 256, 256, 0, stream>>>(deg, dis);
    scan1_kernel<<<SCAN_NBLK, 256, 0, stream>>>(counts, offsets, bsum);
    scan2_kernel<<<1, 256, 0, stream>>>(bsum, bscan);
    scan3_kernel<<<SCAN_NBLK, 256, 0, stream>>>(offsets, bscan);
    fill_kernel<<<(N_EDGES + 255) / 256, 256, 0, stream>>>(adj, aw, dis, offsets, cursor, csr_src, csr_val);

    // weight pack + x convert (all 3)
    convert_w_kernel<<<(D_OUT * D_K + 255) / 256, 256, 0, stream>>>(W, Wres, Wcb);
    {
        size_t total = (size_t)3 * M_PAD * D_IN / 8;
        convert_x_kernel<<<(unsigned)((total + 255) / 256), 256, 0, stream>>>(x0, x1, x2, Xcat);
    }

    // gathers: all 3 convs in one launch (grid.y = conv)
    {
        dim3 ggrid(N_NODES / 4, 3);
        gather_kernel<<<ggrid, 256, 0, stream>>>(Xcat, offsets, csr_src, csr_val, dis);
    }

    // one batched GEMM, 1-D swizzled grid, fused leaky-relu epilogue
    gemm_kernel<<<dim3(GEMM_NWG), 256, 0, stream>>>(Xcat, Wcb, out);
}